// Round 10
// baseline (133.718 us; speedup 1.0000x reference)
//
#include <hip/hip_runtime.h>
#include <cstddef>

#define NCOLS 985
#define SROWS 4                     // rows per wave-private supertile
#define SLABF (SROWS * NCOLS)       // 3940 floats = 15760 B (== 0 mod 16)
#define NQ4   (SLABF / 4)           // 985 float4 units
#define GSTR  176                   // per-wave G slots

__global__ __launch_bounds__(256) void sindy_kernel(const float* __restrict__ z,
                                                    const float* __restrict__ dz,
                                                    float* __restrict__ out, int batch,
                                                    int nsup, int nwaves) {
  __shared__ unsigned short mtab[1024];   // col -> a | b<<8 (G indices)
  __shared__ unsigned short ptab[136];    // pair p -> i | j<<4
  __shared__ float G[4][GSTR];            // per-wave factor array
  __shared__ alignas(16) float slab[4][SLABF];   // per-wave 4-row staging slab

  const int tid = threadIdx.x;

  // ---- build static tables (once per block) ----
  for (int e = tid; e < 1024; e += 256) {
    int a, b;
    if (e < 153)       { a = (e == 0) ? 0 : e; b = 0; }
    else if (e < 969)  {
      int t = e - 153, i = 0;
      for (;;) { int c = (16 - i) * (17 - i) / 2; if (t < c) break; t -= c; ++i; }
      int j = i; while (t >= 16 - j) { t -= 16 - j; ++j; }
      int k = j + t;
      int p = i * 16 - i * (i - 1) / 2 + (j - i);
      a = 17 + p; b = 1 + k;                                      // (zi*zj) * zk
    }
    else if (e < 985)  { a = 153 + (e - 969); b = 0; }
    else               { a = 169; b = 169; }
    mtab[e] = (unsigned short)(a | (b << 8));
  }
  for (int e = tid; e < 136; e += 256) {
    int p = e, i = 0; while (p >= 16 - i) { p -= 16 - i; ++i; }
    ptab[e] = (unsigned short)(i | ((i + p) << 4));
  }
  __syncthreads();   // tables ready — the ONLY block-wide barrier

  const int w = tid >> 6, l = tid & 63;

  // per-lane static table entries in VGPRs (fixed across rows)
  unsigned short mt[16];
  #pragma unroll
  for (int wd = 0; wd < 16; ++wd) mt[wd] = mtab[wd * 64 + l];
  const unsigned pe0 = ptab[l];
  const unsigned pe1 = ptab[64 + l];
  const unsigned pe2 = ptab[(128 + l < 136) ? (128 + l) : 135];

  float* Gw = G[w];
  float* sw = slab[w];
  const int gwave = blockIdx.x * 4 + w;

  for (int st = gwave; st < nsup; st += nwaves) {
    const int row0 = st * SROWS;

    // ---- compute: 4 rows into the wave-private slab ----
    #pragma unroll
    for (int rr = 0; rr < SROWS; ++rr) {
      const int row = row0 + rr;                  // wave-uniform
      if (row < batch) {
        // stage G[0..16] (1, zc) + zero pad 169..175
        float gval = 0.f;
        if (l == 0)       gval = 1.0f;
        else if (l < 9)   gval = z [(size_t)row * 8 + (l - 1)];
        else if (l < 17)  gval = dz[(size_t)row * 8 + (l - 9)];
        const int gaddr = (l < 17) ? l : (152 + l);
        if (l < 24) Gw[gaddr] = gval;

        const float sv = __shfl(gval, l + 1);
        if (l < 16) Gw[153 + l] = __sinf(sv);
        __builtin_amdgcn_sched_barrier(0);        // G base writes before pair gathers

        // pairs G[17..152] (same-wave DS is in-order)
        {
          float a0 = Gw[1 + (pe0 & 15)], b0 = Gw[1 + (pe0 >> 4)];
          Gw[17 + l] = a0 * b0;
          float a1 = Gw[1 + (pe1 & 15)], b1 = Gw[1 + (pe1 >> 4)];
          Gw[17 + 64 + l] = a1 * b1;
          if (l < 8) {
            float a2 = Gw[1 + (pe2 & 15)], b2 = Gw[1 + (pe2 >> 4)];
            Gw[17 + 128 + l] = a2 * b2;
          }
        }
        __builtin_amdgcn_sched_barrier(0);        // pair writes before main gathers

        // main: 16 windows x 64 cols -> slab row rr
        float* rb = sw + rr * NCOLS;
        #pragma unroll
        for (int wd = 0; wd < 16; ++wd) {
          const unsigned e = mt[wd];
          const float v = Gw[e & 255] * Gw[e >> 8];
          if (wd < 15)              rb[wd * 64 + l] = v;
          else if (l < NCOLS - 960) rb[960 + l] = v;
        }
        __builtin_amdgcn_sched_barrier(0);        // row writes before next row / drain
      }
    }

    // ---- drain: wave-private, no barrier, no vmcnt(0) — stores just stream ----
    if (row0 + SROWS <= batch) {
      float4* __restrict__ dst = (float4*)(out + (size_t)row0 * NCOLS);
      const float4* srcq = (const float4*)sw;
      #pragma unroll 4
      for (int u = l; u < NQ4; u += 64) {
        dst[u] = srcq[u];                          // ds_read_b128 + store_dwordx4
      }
    } else {
      const int nel = (batch - row0) * NCOLS;
      float* __restrict__ dst = out + (size_t)row0 * NCOLS;
      for (int u = l; u < nel; u += 64) dst[u] = sw[u];
    }
    __builtin_amdgcn_sched_barrier(0);             // drain reads before next supertile's writes
  }
}

extern "C" void kernel_launch(void* const* d_in, const int* in_sizes, int n_in,
                              void* d_out, int out_size, void* d_ws, size_t ws_size,
                              hipStream_t stream) {
  const float* z  = (const float*)d_in[0];
  const float* dz = (const float*)d_in[1];
  float* out = (float*)d_out;
  const int batch = in_sizes[0] / 8;   // LATENT_DIM = 8

  const int nsup   = (batch + SROWS - 1) / SROWS;   // 32768 supertiles
  const int blocks = 512;                            // 2 resident blocks/CU, all resident
  const int nwaves = blocks * 4;                     // 2048 waves, 16 supertiles each
  sindy_kernel<<<blocks, 256, 0, stream>>>(z, dz, out, batch, nsup, nwaves);
}

// Round 11
// 127.794 us; speedup vs baseline: 1.0464x; 1.0464x over previous
//
#include <hip/hip_runtime.h>
#include <cstddef>

#define NCOLS  985
#define GROWS  4                      // rows per group -> flat 16B-aligned segment
#define GFLT   (GROWS * NCOLS)        // 3940 floats per group (15760 B % 16 == 0)
#define NU     (GFLT / 4)             // 985 float4 units per group
#define GSTR   176                    // per-row G slots

__global__ __launch_bounds__(256) void sindy_kernel(const float* __restrict__ z,
                                                    const float* __restrict__ dz,
                                                    float* __restrict__ out, int batch,
                                                    int ngroups, int nwaves) {
  __shared__ alignas(16) unsigned int utab[GFLT];  // elem -> (r*176+a) | (r*176+b)<<16
  __shared__ unsigned short ptab[136];             // pair p -> i | j<<4
  __shared__ float G4[4][GROWS * GSTR];            // per-wave: 4 rows of factors

  const int tid = threadIdx.x;

  // ---- build tables (once per block) ----
  for (int fe = tid; fe < GFLT; fe += 256) {
    const int r   = fe / NCOLS;           // row offset within group (0..3)
    const int col = fe - r * NCOLS;
    int a, b;
    if (col < 153)      { a = (col == 0) ? 0 : col; b = 0; }       // 1, zc, pairs (x G[0]=1)
    else if (col < 969) {                                          // triples: (zi*zj) * zk
      int t = col - 153, i = 0;
      for (;;) { int c = (16 - i) * (17 - i) / 2; if (t < c) break; t -= c; ++i; }
      int j = i; while (t >= 16 - j) { t -= 16 - j; ++j; }
      int k = j + t;
      int p = i * 16 - i * (i - 1) / 2 + (j - i);
      a = 17 + p; b = 1 + k;
    }
    else                { a = 153 + (col - 969); b = 0; }          // sines
    const unsigned base = (unsigned)(r * GSTR);
    utab[fe] = (base + (unsigned)a) | ((base + (unsigned)b) << 16);
  }
  for (int e = tid; e < 136; e += 256) {
    int p = e, i = 0; while (p >= 16 - i) { p -= 16 - i; ++i; }
    ptab[e] = (unsigned short)(i | ((i + p) << 4));
  }
  __syncthreads();   // tables ready — the ONLY block-wide barrier

  const int w = tid >> 6, l = tid & 63;

  const unsigned pe0 = ptab[l];
  const unsigned pe1 = ptab[64 + l];
  const unsigned pe2 = ptab[(128 + l < 136) ? (128 + l) : 135];

  float* Gw = G4[w];
  const int gwave = blockIdx.x * 4 + w;

  for (int grp = gwave; grp < ngroups; grp += nwaves) {
    const int row0 = grp * GROWS;

    // ---- stage 4 rows of G factors (wave-private; same-wave DS is in-order) ----
    #pragma unroll
    for (int rr = 0; rr < GROWS; ++rr) {
      const int row = row0 + rr;
      float gval = 0.f;
      if (l == 0)       gval = 1.0f;
      else if (l < 9)   gval = z [(size_t)row * 8 + (l - 1)];
      else if (l < 17)  gval = dz[(size_t)row * 8 + (l - 9)];
      float* Gr = Gw + rr * GSTR;
      const int gaddr = (l < 17) ? l : (152 + l);                  // pad 169..175 = 0
      if (l < 24) Gr[gaddr] = gval;

      const float sv = __shfl(gval, l + 1);
      if (l < 16) Gr[153 + l] = __sinf(sv);
      __builtin_amdgcn_sched_barrier(0);     // G base writes before pair gathers

      {
        float a0 = Gr[1 + (pe0 & 15)], b0 = Gr[1 + (pe0 >> 4)];
        Gr[17 + l] = a0 * b0;
        float a1 = Gr[1 + (pe1 & 15)], b1 = Gr[1 + (pe1 >> 4)];
        Gr[17 + 64 + l] = a1 * b1;
        if (l < 8) {
          float a2 = Gr[1 + (pe2 & 15)], b2 = Gr[1 + (pe2 >> 4)];
          Gr[17 + 128 + l] = a2 * b2;
        }
      }
      __builtin_amdgcn_sched_barrier(0);     // pair writes before unit gathers
    }

    // ---- gather + store: one aligned float4 per lane per iter, stores stream ----
    float4* __restrict__ dst = (float4*)(out + (size_t)row0 * NCOLS);
    const uint4* ut = (const uint4*)utab;
    #pragma unroll
    for (int it = 0; it < 16; ++it) {
      const int u = it * 64 + l;
      if (it < 15 || l < NU - 960) {         // tail iter: lanes 0..24
        const uint4 e = ut[u];
        float4 v;
        v.x = Gw[e.x & 0xffffu] * Gw[e.x >> 16];
        v.y = Gw[e.y & 0xffffu] * Gw[e.y >> 16];
        v.z = Gw[e.z & 0xffffu] * Gw[e.z >> 16];
        v.w = Gw[e.w & 0xffffu] * Gw[e.w >> 16];
        dst[u] = v;                          // global_store_dwordx4, 16B-aligned
      }
    }
    __builtin_amdgcn_sched_barrier(0);       // unit gathers before next group's staging
  }

  // ---- generic tail (batch % 4 != 0): never taken for batch=131072 ----
  const int rem0 = ngroups * GROWS;
  if (rem0 < batch && gwave == 0) {
    for (int row = rem0; row < batch; ++row) {
      float gval = 0.f;
      if (l == 0)       gval = 1.0f;
      else if (l < 9)   gval = z [(size_t)row * 8 + (l - 1)];
      else if (l < 17)  gval = dz[(size_t)row * 8 + (l - 9)];
      float* Gr = Gw;
      const int gaddr = (l < 17) ? l : (152 + l);
      if (l < 24) Gr[gaddr] = gval;
      const float sv = __shfl(gval, l + 1);
      if (l < 16) Gr[153 + l] = __sinf(sv);
      __builtin_amdgcn_sched_barrier(0);
      {
        float a0 = Gr[1 + (pe0 & 15)], b0 = Gr[1 + (pe0 >> 4)];
        Gr[17 + l] = a0 * b0;
        float a1 = Gr[1 + (pe1 & 15)], b1 = Gr[1 + (pe1 >> 4)];
        Gr[17 + 64 + l] = a1 * b1;
        if (l < 8) {
          float a2 = Gr[1 + (pe2 & 15)], b2 = Gr[1 + (pe2 >> 4)];
          Gr[17 + 128 + l] = a2 * b2;
        }
      }
      __builtin_amdgcn_sched_barrier(0);
      float* orow = out + (size_t)row * NCOLS;
      for (int wd = 0; wd < 16; ++wd) {
        const int col = wd * 64 + l;
        if (col < NCOLS) {
          const unsigned e = utab[col];      // row-0 entries of utab
          orow[col] = Gw[e & 0xffffu] * Gw[e >> 16];
        }
      }
      __builtin_amdgcn_sched_barrier(0);
    }
  }
}

extern "C" void kernel_launch(void* const* d_in, const int* in_sizes, int n_in,
                              void* d_out, int out_size, void* d_ws, size_t ws_size,
                              hipStream_t stream) {
  const float* z  = (const float*)d_in[0];
  const float* dz = (const float*)d_in[1];
  float* out = (float*)d_out;
  const int batch = in_sizes[0] / 8;   // LATENT_DIM = 8

  const int blocks  = 2048;            // 8192 waves; 5 blocks/CU resident (LDS-capped)
  const int nwaves  = blocks * 4;
  const int ngroups = batch / GROWS;   // 32768 full 4-row groups
  sindy_kernel<<<blocks, 256, 0, stream>>>(z, dz, out, batch, ngroups, nwaves);
}

// Round 12
// 122.601 us; speedup vs baseline: 1.0907x; 1.0424x over previous
//
#include <hip/hip_runtime.h>
#include <cstddef>

#define NCOLS 985
#define GROWS 4                       // rows per group -> flat 16B-aligned segment
#define GFLT  (GROWS * NCOLS)         // 3940 floats per group
#define NU    (GFLT / 4)              // 985 float4 units per group
#define GSTR  176                     // per-row G slots

__global__ __launch_bounds__(256) void sindy_kernel(const float* __restrict__ z,
                                                    const float* __restrict__ dz,
                                                    float* __restrict__ out, int batch,
                                                    int ngroups, int nwaves) {
  __shared__ alignas(16) unsigned int utab[GFLT];   // elem -> goff | midx<<16 (base = r*176)
  __shared__ unsigned int utab2[1024];              // unit -> goff0 | midx<<10 | slow<<20
  __shared__ unsigned short ptab[136];              // pair p -> i | j<<4
  __shared__ float G4[4][GROWS * GSTR];             // per-wave: 4 rows of factors

  const int tid = threadIdx.x;

  // ---- per-element table: out[c] = G[goff] * G[midx] ----
  // deg3 block with leading i == zc[i] * (contiguous suffix of the deg2 array)
  for (int fe = tid; fe < GFLT; fe += 256) {
    const int r = fe / NCOLS;
    const int c = fe - r * NCOLS;
    int goff, midx;
    if (c < 153)      { goff = c; midx = 0; }                 // 1, zc, deg2 (x G[0]=1)
    else if (c < 969) {
      int t = c - 153, i = 0;
      for (;;) { int cnt = (16 - i) * (17 - i) / 2; if (t < cnt) break; t -= cnt; ++i; }
      goff = 17 + (136 - (16 - i) * (17 - i) / 2) + t;        // suffix start + offset
      midx = 1 + i;                                            // x zc[i]
    }
    else              { goff = 153 + (c - 969); midx = 0; }   // sines
    const unsigned base = (unsigned)(r * GSTR);
    utab[fe] = (base + (unsigned)goff) | ((base + (unsigned)midx) << 16);
  }
  for (int e = tid; e < 136; e += 256) {
    int p = e, i = 0; while (p >= 16 - i) { p -= 16 - i; ++i; }
    ptab[e] = (unsigned short)(i | ((i + p) << 4));
  }
  __syncthreads();   // utab ready (utab2 derives from it)

  // ---- per-unit table: normal iff goffs consecutive and midx uniform ----
  for (int u = tid; u < 1024; u += 256) {
    unsigned pk = 0;
    if (u < NU) {
      const unsigned e0 = utab[4*u], e1 = utab[4*u+1], e2 = utab[4*u+2], e3 = utab[4*u+3];
      const unsigned g0 = e0 & 0xffffu, m0 = e0 >> 16;
      const bool normal = ((e1 & 0xffffu) == g0 + 1) && ((e2 & 0xffffu) == g0 + 2) &&
                          ((e3 & 0xffffu) == g0 + 3) &&
                          ((e1 >> 16) == m0) && ((e2 >> 16) == m0) && ((e3 >> 16) == m0);
      pk = g0 | (m0 << 10) | (normal ? 0u : (1u << 20));
    }
    utab2[u] = pk;
  }
  __syncthreads();   // tables ready — last block-wide barrier

  const int w = tid >> 6, l = tid & 63;
  const unsigned pe0 = ptab[l];
  const unsigned pe1 = ptab[64 + l];
  const unsigned pe2 = ptab[(128 + l < 136) ? (128 + l) : 135];

  // hoist this lane's 16 unit entries to VGPRs (fixed across groups)
  unsigned ue[16];
  #pragma unroll
  for (int s = 0; s < 16; ++s) ue[s] = utab2[s * 64 + l];

  float* Gw = G4[w];
  const int gwave = blockIdx.x * 4 + w;

  for (int grp = gwave; grp < ngroups; grp += nwaves) {
    const int row0 = grp * GROWS;

    // ---- stage 4 rows of G factors (wave-private; same-wave DS in-order) ----
    #pragma unroll
    for (int rr = 0; rr < GROWS; ++rr) {
      const int row = row0 + rr;
      float gval = 0.f;
      if (l == 0)       gval = 1.0f;
      else if (l < 9)   gval = z [(size_t)row * 8 + (l - 1)];
      else if (l < 17)  gval = dz[(size_t)row * 8 + (l - 9)];
      float* Gr = Gw + rr * GSTR;
      const int gaddr = (l < 17) ? l : (152 + l);              // pad 169..175 = 0
      if (l < 24) Gr[gaddr] = gval;

      const float sv = __shfl(gval, l + 1);
      if (l < 16) Gr[153 + l] = __sinf(sv);
      __builtin_amdgcn_sched_barrier(0);     // G base writes before pair gathers

      {
        float a0 = Gr[1 + (pe0 & 15)], b0 = Gr[1 + (pe0 >> 4)];
        Gr[17 + l] = a0 * b0;
        float a1 = Gr[1 + (pe1 & 15)], b1 = Gr[1 + (pe1 >> 4)];
        Gr[17 + 64 + l] = a1 * b1;
        if (l < 8) {
          float a2 = Gr[1 + (pe2 & 15)], b2 = Gr[1 + (pe2 >> 4)];
          Gr[17 + 128 + l] = a2 * b2;
        }
      }
      __builtin_amdgcn_sched_barrier(0);     // pair writes before unit reads
    }

    // ---- unit loop: 3 DS per float4 (normal), stores stream, no barriers ----
    float4* __restrict__ dst = (float4*)(out + (size_t)row0 * NCOLS);
    #pragma unroll
    for (int s = 0; s < 16; ++s) {
      if (s < 15 || l < NU - 960) {          // tail step: lanes 0..24
        const unsigned pk = ue[s];
        const int u = s * 64 + l;
        float4 v;
        if (!(pk & (1u << 20))) {
          const unsigned g0 = pk & 0x3ffu;
          const float m = Gw[(pk >> 10) & 0x3ffu];
          const float a0 = Gw[g0], a1 = Gw[g0 + 1], a2 = Gw[g0 + 2], a3 = Gw[g0 + 3];
          v.x = a0 * m; v.y = a1 * m; v.z = a2 * m; v.w = a3 * m;
        } else {
          const uint4 e = *(const uint4*)&utab[4 * u];         // ds_read_b128
          v.x = Gw[e.x & 0xffffu] * Gw[e.x >> 16];
          v.y = Gw[e.y & 0xffffu] * Gw[e.y >> 16];
          v.z = Gw[e.z & 0xffffu] * Gw[e.z >> 16];
          v.w = Gw[e.w & 0xffffu] * Gw[e.w >> 16];
        }
        dst[u] = v;                           // aligned global_store_dwordx4
      }
    }
    __builtin_amdgcn_sched_barrier(0);        // unit reads before next group's staging
  }

  // ---- generic tail (batch % 4 != 0): never taken for batch = 131072 ----
  const int rem0 = ngroups * GROWS;
  if (rem0 < batch && gwave == 0) {
    for (int row = rem0; row < batch; ++row) {
      float gval = 0.f;
      if (l == 0)       gval = 1.0f;
      else if (l < 9)   gval = z [(size_t)row * 8 + (l - 1)];
      else if (l < 17)  gval = dz[(size_t)row * 8 + (l - 9)];
      const int gaddr = (l < 17) ? l : (152 + l);
      if (l < 24) Gw[gaddr] = gval;
      const float sv = __shfl(gval, l + 1);
      if (l < 16) Gw[153 + l] = __sinf(sv);
      __builtin_amdgcn_sched_barrier(0);
      {
        float a0 = Gw[1 + (pe0 & 15)], b0 = Gw[1 + (pe0 >> 4)];
        Gw[17 + l] = a0 * b0;
        float a1 = Gw[1 + (pe1 & 15)], b1 = Gw[1 + (pe1 >> 4)];
        Gw[17 + 64 + l] = a1 * b1;
        if (l < 8) {
          float a2 = Gw[1 + (pe2 & 15)], b2 = Gw[1 + (pe2 >> 4)];
          Gw[17 + 128 + l] = a2 * b2;
        }
      }
      __builtin_amdgcn_sched_barrier(0);
      float* orow = out + (size_t)row * NCOLS;
      for (int wd = 0; wd < 16; ++wd) {
        const int col = wd * 64 + l;
        if (col < NCOLS) {
          const unsigned e = utab[col];       // row-0 entries
          orow[col] = Gw[e & 0xffffu] * Gw[e >> 16];
        }
      }
      __builtin_amdgcn_sched_barrier(0);
    }
  }
}

extern "C" void kernel_launch(void* const* d_in, const int* in_sizes, int n_in,
                              void* d_out, int out_size, void* d_ws, size_t ws_size,
                              hipStream_t stream) {
  const float* z  = (const float*)d_in[0];
  const float* dz = (const float*)d_in[1];
  float* out = (float*)d_out;
  const int batch = in_sizes[0] / 8;   // LATENT_DIM = 8

  const int blocks  = 2048;            // 8192 waves, grid-strided over groups
  const int nwaves  = blocks * 4;
  const int ngroups = batch / GROWS;   // 32768 full 4-row groups
  sindy_kernel<<<blocks, 256, 0, stream>>>(z, dz, out, batch, ngroups, nwaves);
}

// Round 13
// 117.192 us; speedup vs baseline: 1.1410x; 1.0462x over previous
//
#include <hip/hip_runtime.h>
#include <cstddef>

#define NCOLS 985
#define TROWS 4                    // rows per tile
#define TILEF (TROWS * NCOLS)      // 3940 floats (15760 B, 16B-aligned per tile)
#define NU    (TILEF / 4)          // 985 float4 units
#define GSTR  176                  // per-wave G slots

__global__ __launch_bounds__(256) void sindy_kernel(const float* __restrict__ z,
                                                    const float* __restrict__ dz,
                                                    float* __restrict__ out, int batch,
                                                    int ntiles) {
  __shared__ unsigned int ctab[1024];            // col -> goff | midx<<16 (suffix trick)
  __shared__ unsigned short ptab[136];           // pair p -> i | j<<4
  __shared__ float G4[4][GSTR];                  // per-wave factor row
  __shared__ alignas(16) float buf[2][TILEF];    // double-buffered output tile

  const int tid = threadIdx.x;

  // ---- build tables (once per block) ----
  for (int c = tid; c < 1024; c += 256) {
    unsigned goff, midx;
    if (c < 153)      { goff = (unsigned)c; midx = 0; }          // 1, zc, deg2 (x G[0]=1)
    else if (c < 969) {                                          // deg3 = deg2[suffix] * zc[i]
      int t = c - 153, i = 0;
      for (;;) { int cnt = (16 - i) * (17 - i) / 2; if (t < cnt) break; t -= cnt; ++i; }
      goff = (unsigned)(17 + (136 - (16 - i) * (17 - i) / 2) + t);
      midx = (unsigned)(1 + i);
    }
    else if (c < 985) { goff = (unsigned)(153 + (c - 969)); midx = 0; }  // sines
    else              { goff = 169; midx = 169; }                        // pad -> 0*0
    ctab[c] = goff | (midx << 16);
  }
  for (int e = tid; e < 136; e += 256) {
    int p = e, i = 0; while (p >= 16 - i) { p -= 16 - i; ++i; }
    ptab[e] = (unsigned short)(i | ((i + p) << 4));
  }
  __syncthreads();

  const int w = tid >> 6, l = tid & 63;

  // hoist per-lane table entries to VGPRs (fixed across tiles)
  unsigned ct[16];
  #pragma unroll
  for (int s = 0; s < 16; ++s) ct[s] = ctab[s * 64 + l];
  const unsigned pe0 = ptab[l];
  const unsigned pe1 = ptab[64 + l];
  const unsigned pe2 = ptab[(128 + l < 136) ? (128 + l) : 135];

  float* Gw = G4[w];

  // ---- compute one row into rb (wave-private G; same-wave DS is in-order) ----
  auto compute_row = [&](int row, float* rb) {
    float gval = 0.f;
    if (l == 0)       gval = 1.0f;
    else if (l < 9)   gval = z [(size_t)row * 8 + (l - 1)];
    else if (l < 17)  gval = dz[(size_t)row * 8 + (l - 9)];
    const int gaddr = (l < 17) ? l : (152 + l);                  // zero pad 169..175
    if (l < 24) Gw[gaddr] = gval;

    const float sv = __shfl(gval, l + 1);
    if (l < 16) Gw[153 + l] = __sinf(sv);
    __builtin_amdgcn_sched_barrier(0);        // G base writes before pair gathers

    {
      float a0 = Gw[1 + (pe0 & 15)], b0 = Gw[1 + (pe0 >> 4)];
      Gw[17 + l] = a0 * b0;
      float a1 = Gw[1 + (pe1 & 15)], b1 = Gw[1 + (pe1 >> 4)];
      Gw[17 + 64 + l] = a1 * b1;
      if (l < 8) {
        float a2 = Gw[1 + (pe2 & 15)], b2 = Gw[1 + (pe2 >> 4)];
        Gw[17 + 128 + l] = a2 * b2;
      }
    }
    __builtin_amdgcn_sched_barrier(0);        // pair writes before window gathers

    #pragma unroll
    for (int s = 0; s < 16; ++s) {
      const unsigned e = ct[s];
      const float v = Gw[e & 0xffffu] * Gw[e >> 16];   // consecutive + broadcast reads
      if (s < 15)      rb[s * 64 + l] = v;
      else if (l < 25) rb[960 + l] = v;
    }
  };

  // ---- drain one tile: flat aligned float4 stores, NO completion wait here ----
  auto drain_tile = [&](const float* src, float4* __restrict__ dst, int nelem) {
    if (nelem == TILEF) {
      const float4* s4 = (const float4*)src;
      #pragma unroll
      for (int k = 0; k < 4; ++k) {
        const int u = k * 256 + tid;
        if (k < 3 || u < NU) dst[u] = s4[u];
      }
    } else {
      float* __restrict__ d = (float*)dst;
      for (int u = tid; u < nelem; u += 256) d[u] = src[u];
    }
  };

  // ---- software pipeline: [drain t | compute t+1] per barrier ----
  int t = blockIdx.x;
  if (t >= ntiles) return;
  int p = 0;
  {
    const int row = t * TROWS + w;
    if (row < batch) compute_row(row, buf[0] + w * NCOLS);
  }
  __syncthreads();

  for (int tn = t + gridDim.x; tn < ntiles; tn += gridDim.x) {
    const int nel = min(TILEF, batch * NCOLS - t * TILEF);
    drain_tile(buf[p], (float4*)(out + (size_t)t * TILEF), nel);   // stores stream
    {
      const int row = tn * TROWS + w;
      if (row < batch) compute_row(row, buf[p ^ 1] + w * NCOLS);   // hides store latency
    }
    __syncthreads();   // vmcnt(0) here: stores had a full compute phase to land
    p ^= 1; t = tn;
  }
  {
    const int nel = min(TILEF, batch * NCOLS - t * TILEF);
    drain_tile(buf[p], (float4*)(out + (size_t)t * TILEF), nel);
  }
}

extern "C" void kernel_launch(void* const* d_in, const int* in_sizes, int n_in,
                              void* d_out, int out_size, void* d_ws, size_t ws_size,
                              hipStream_t stream) {
  const float* z  = (const float*)d_in[0];
  const float* dz = (const float*)d_in[1];
  float* out = (float*)d_out;
  const int batch = in_sizes[0] / 8;   // LATENT_DIM = 8

  const int ntiles = (batch + TROWS - 1) / TROWS;   // 32768
  const int blocks = 2048;                           // 16 tiles/block, 4 blocks/CU
  sindy_kernel<<<blocks, 256, 0, stream>>>(z, dz, out, batch, ntiles);
}